// Round 3
// baseline (363.049 us; speedup 1.0000x reference)
//
#include <hip/hip_runtime.h>
#include <hip/hip_bf16.h>
#include <math.h>

#define D_MODEL 1024
#define SEQ 1024
#define BATCH 16
#define NROWS (BATCH * SEQ)   // 16384
#define KTILES 16             // D_MODEL / 64

typedef __bf16 bf16x8 __attribute__((ext_vector_type(8)));
typedef __bf16 bf16x4 __attribute__((ext_vector_type(4)));
typedef float f32x4 __attribute__((ext_vector_type(4)));
typedef __hip_bfloat16 bf16;

__device__ __forceinline__ float bf2f(bf16 v) { return __bfloat162float(v); }
__device__ __forceinline__ bf16 f2bf(float v) { return __float2bfloat16(v); }

__device__ __forceinline__ void gload_lds16(const bf16* g, bf16* l) {
    __builtin_amdgcn_global_load_lds(
        (const __attribute__((address_space(1))) void*)g,
        (__attribute__((address_space(3))) void*)l, 16, 0, 0);
}

#define VM_WAIT(n)   asm volatile("s_waitcnt vmcnt(" #n ")" ::: "memory")
#define LGKM_WAIT(n) asm volatile("s_waitcnt lgkmcnt(" #n ")" ::: "memory")
#define BAR()        __builtin_amdgcn_s_barrier()

// 256 blocks -> 8 XCDs x 32. Each XCD: 8 M-bands x 4 N-tiles concurrent.
__device__ __forceinline__ void tile_coords256(int lin, int& m0, int& n0) {
    const int xcd = lin & 7;
    const int loc = lin >> 3;            // 0..31
    m0 = (xcd * 8 + (loc >> 2)) * 256;
    n0 = (loc & 3) * 256;
}

// ---------------- all 4 weights fp32 -> bf16, one dispatch ----------------
__global__ void conv_w4_kernel(const float* __restrict__ s0, const float* __restrict__ s1,
                               const float* __restrict__ s2, const float* __restrict__ s3,
                               bf16* __restrict__ dst) {
    const float* srcs[4] = {s0, s1, s2, s3};
    const float* src = srcs[blockIdx.y];
    bf16* d = dst + (size_t)blockIdx.y * (D_MODEL * D_MODEL);
    int i = blockIdx.x * blockDim.x + threadIdx.x;
    int stride = gridDim.x * blockDim.x;
    for (; i < D_MODEL * D_MODEL; i += stride) d[i] = f2bf(src[i]);
}

// ---------------- fused LayerNorm + time-mix: one wave per row ----------------
__global__ __launch_bounds__(256) void lnmix_kernel(
    const float* __restrict__ x, const float* __restrict__ gamma, const float* __restrict__ beta,
    const float* __restrict__ tmk, const float* __restrict__ tmv, const float* __restrict__ tmr,
    bf16* __restrict__ xk, bf16* __restrict__ xv, bf16* __restrict__ xr)
{
    const int wave = threadIdx.x >> 6, lane = threadIdx.x & 63;
    const int row = blockIdx.x * 4 + wave;
    const int t = row & (SEQ - 1);
    const size_t base = (size_t)row * D_MODEL;

    float4 vc[4], vp[4];
    float sc = 0.f, sc2 = 0.f, sp = 0.f, sp2 = 0.f;
#pragma unroll
    for (int c = 0; c < 4; c++) {
        const int d = lane * 4 + c * 256;
        vc[c] = *reinterpret_cast<const float4*>(x + base + d);
        if (t == 0) { vp[c] = make_float4(0.f, 0.f, 0.f, 0.f); }
        else        { vp[c] = *reinterpret_cast<const float4*>(x + base - D_MODEL + d); }
        sc  += vc[c].x + vc[c].y + vc[c].z + vc[c].w;
        sc2 += vc[c].x * vc[c].x + vc[c].y * vc[c].y + vc[c].z * vc[c].z + vc[c].w * vc[c].w;
        sp  += vp[c].x + vp[c].y + vp[c].z + vp[c].w;
        sp2 += vp[c].x * vp[c].x + vp[c].y * vp[c].y + vp[c].z * vp[c].z + vp[c].w * vp[c].w;
    }
#pragma unroll
    for (int off = 1; off < 64; off <<= 1) {
        sc  += __shfl_xor(sc, off);
        sc2 += __shfl_xor(sc2, off);
        sp  += __shfl_xor(sp, off);
        sp2 += __shfl_xor(sp2, off);
    }
    const float muc = sc * (1.0f / D_MODEL);
    const float rc  = rsqrtf(sc2 * (1.0f / D_MODEL) - muc * muc + 1e-5f);
    const float mup = sp * (1.0f / D_MODEL);
    const float rp  = rsqrtf(sp2 * (1.0f / D_MODEL) - mup * mup + 1e-5f);

#pragma unroll
    for (int c = 0; c < 4; c++) {
        const int d = lane * 4 + c * 256;
        float4 g  = *reinterpret_cast<const float4*>(gamma + d);
        float4 b  = *reinterpret_cast<const float4*>(beta + d);
        float4 mk = *reinterpret_cast<const float4*>(tmk + d);
        float4 mv = *reinterpret_cast<const float4*>(tmv + d);
        float4 mr = *reinterpret_cast<const float4*>(tmr + d);
        float cn[4], pn[4];
        cn[0] = (vc[c].x - muc) * rc * g.x + b.x;
        cn[1] = (vc[c].y - muc) * rc * g.y + b.y;
        cn[2] = (vc[c].z - muc) * rc * g.z + b.z;
        cn[3] = (vc[c].w - muc) * rc * g.w + b.w;
        if (t == 0) { pn[0] = pn[1] = pn[2] = pn[3] = 0.f; }
        else {
            pn[0] = (vp[c].x - mup) * rp * g.x + b.x;
            pn[1] = (vp[c].y - mup) * rp * g.y + b.y;
            pn[2] = (vp[c].z - mup) * rp * g.z + b.z;
            pn[3] = (vp[c].w - mup) * rp * g.w + b.w;
        }
        const float mkv[4] = {mk.x, mk.y, mk.z, mk.w};
        const float mvv[4] = {mv.x, mv.y, mv.z, mv.w};
        const float mrv[4] = {mr.x, mr.y, mr.z, mr.w};
        bf16x4 ok, ov, orr;
#pragma unroll
        for (int e = 0; e < 4; e++) {
            ok[e]  = (__bf16)(mkv[e] * cn[e] + (1.0f - mkv[e]) * pn[e]);
            ov[e]  = (__bf16)(mvv[e] * cn[e] + (1.0f - mvv[e]) * pn[e]);
            orr[e] = (__bf16)(mrv[e] * cn[e] + (1.0f - mrv[e]) * pn[e]);
        }
        *reinterpret_cast<bf16x4*>(xk + base + d) = ok;
        *reinterpret_cast<bf16x4*>(xv + base + d) = ov;
        *reinterpret_cast<bf16x4*>(xr + base + d) = orr;
    }
}

// ============================================================================
// 256x256 GEMM core, BK=64, 8 waves (2Mx4N), CROSS-PHASE FRAGMENT PREFETCH.
// Every fragment group is ds_read one phase before its consuming MFMA quadrant;
// pre-MFMA waits are counted lgkmcnt (drain previous phase's reads only), so
// the LDS service queue overlaps the MFMA bursts instead of alternating.
// Quadrants: Q1=alo*blo, Q2=alo*bhi, Q3=ahi*bhi, Q4=ahi*blo (each group live
// <=2 phases -> all single-buffered: 96 frag VGPRs).
// A halves in LDS (linear): AL1 rows0-63 @0, AL2 64-127 @4096, AL3 128-191
// @8192, AL4 192-255 @12288. alo touches AL1/AL3, ahi AL2/AL4.
// Stage slots per tile t (2 gloads each):
//   P1: B12(t+1)->nxt  P2: B34(t+1)->nxt  P3: AL13(t+2)->cur  P4: AL24(t+2)->cur
// Waits: vmcnt(6) @P2 (covers AL13(t+1), issued 3 phases prior),
//        vmcnt(4) @P4 (covers B(t+1)+AL24(t+1), issued >=2 phases prior).
// One barrier per phase; all LDS WAR hazards >=2 barriers apart (verified).
// ============================================================================
__device__ __forceinline__ void gemm256_core(
    const bf16* __restrict__ A, const bf16* __restrict__ W,
    bf16* __restrict__ AsB, bf16* __restrict__ BsB,
    int m0, int n0, f32x4 (&acc)[8][4])
{
    const int tid  = threadIdx.x;
    const int wave = tid >> 6, lane = tid & 63;
    const int wm = wave >> 2, wn = wave & 3;
    const int mf = lane & 15, quad = lane >> 4;
    const int srow = tid >> 3;                       // 0..63
    const int scol = ((tid & 7) ^ (srow & 7)) * 8;   // pre-swizzled source chunk
    const int dsub = wave * 512;                     // wave-uniform LDS dest base

    const bf16* Ag = A + (size_t)(m0 + srow) * D_MODEL + scol;
    const bf16* Bg = W + (size_t)(n0 + srow) * D_MODEL + scol;

    bf16x8 alo[4][2], ahi[4][2], blo[2][2], bhi[2][2];

#define RDF(base, R, C) (*reinterpret_cast<const bf16x8*>( \
        (base) + ((R) * 16 + mf) * 64 + ((((C) * 4 + quad) ^ (mf & 7)) * 8)))

    // ---- prologue: t0 {AL13,AL24,B12,B34} + t1 {AL13,AL24} (12 gloads) ----
    gload_lds16(Ag,                   AsB + dsub);               // t0.AL1
    gload_lds16(Ag + 128 * D_MODEL,   AsB +  8192 + dsub);       // t0.AL3
    gload_lds16(Ag +  64 * D_MODEL,   AsB +  4096 + dsub);       // t0.AL2
    gload_lds16(Ag + 192 * D_MODEL,   AsB + 12288 + dsub);       // t0.AL4
    gload_lds16(Bg,                   BsB + dsub);               // t0.B1
    gload_lds16(Bg +  64 * D_MODEL,   BsB +  4096 + dsub);       // t0.B2
    gload_lds16(Bg + 128 * D_MODEL,   BsB +  8192 + dsub);       // t0.B3
    gload_lds16(Bg + 192 * D_MODEL,   BsB + 12288 + dsub);       // t0.B4
    gload_lds16(Ag +                64, AsB + 16384 + dsub);           // t1.AL1
    gload_lds16(Ag + 128 * D_MODEL + 64, AsB + 16384 +  8192 + dsub);  // t1.AL3
    gload_lds16(Ag +  64 * D_MODEL + 64, AsB + 16384 +  4096 + dsub);  // t1.AL2
    gload_lds16(Ag + 192 * D_MODEL + 64, AsB + 16384 + 12288 + dsub);  // t1.AL4
    VM_WAIT(4);                      // t0's 8 landed; t1's A halves still fly
    BAR();

    // pre-read tile0's alo + blo (consumed by kt=0 P1/Q1)
    {
        const bf16* aT0 = AsB + wm * 8192;
        const bf16* bT0 = BsB + wn * 4096;
#pragma unroll
        for (int ii = 0; ii < 4; ++ii) { alo[ii][0] = RDF(aT0, ii, 0); alo[ii][1] = RDF(aT0, ii, 1); }
#pragma unroll
        for (int jj = 0; jj < 2; ++jj) { blo[jj][0] = RDF(bT0, jj, 0); blo[jj][1] = RDF(bT0, jj, 1); }
    }

#pragma unroll 2
    for (int kt = 0; kt < KTILES; ++kt) {
        const int cur = kt & 1;
        const bf16* aT  = AsB + cur * 16384 + wm * 8192;
        const bf16* bT  = BsB + cur * 16384 + wn * 4096;
        const bf16* aTn = AsB + (cur ^ 1) * 16384 + wm * 8192;
        const bf16* bTn = BsB + (cur ^ 1) * 16384 + wn * 4096;
        bf16* An = AsB + cur * 16384;            // A stage target (t+2 -> cur)
        bf16* Bn = BsB + (cur ^ 1) * 16384;      // B stage target (t+1 -> nxt)
        const bf16* Ag2 = Ag + (kt + 2) * 64;
        const bf16* Bg1 = Bg + (kt + 1) * 64;

        // ---- P1: rd bhi(t); stage B12(t+1) ----
#pragma unroll
        for (int jj = 0; jj < 2; ++jj) { bhi[jj][0] = RDF(bT, 2 + jj, 0); bhi[jj][1] = RDF(bT, 2 + jj, 1); }
        if (kt + 1 < KTILES) {
            gload_lds16(Bg1,                Bn + dsub);
            gload_lds16(Bg1 + 64 * D_MODEL, Bn + 4096 + dsub);
        }
        BAR();
        LGKM_WAIT(4);
        __builtin_amdgcn_s_setprio(1);
#pragma unroll
        for (int ii = 0; ii < 4; ++ii)
#pragma unroll
            for (int jj = 0; jj < 2; ++jj)
#pragma unroll
                for (int ks = 0; ks < 2; ++ks)
                    acc[ii][jj] = __builtin_amdgcn_mfma_f32_16x16x32_bf16(alo[ii][ks], blo[jj][ks], acc[ii][jj], 0, 0, 0);
        __builtin_amdgcn_s_setprio(0);

        // ---- P2: rd ahi(t); stage B34(t+1); vmcnt(6) covers AL13(t+1) ----
#pragma unroll
        for (int ii = 0; ii < 4; ++ii) { ahi[ii][0] = RDF(aT, 4 + ii, 0); ahi[ii][1] = RDF(aT, 4 + ii, 1); }
        if (kt + 1 < KTILES) {
            gload_lds16(Bg1 + 128 * D_MODEL, Bn +  8192 + dsub);
            gload_lds16(Bg1 + 192 * D_MODEL, Bn + 12288 + dsub);
        }
        VM_WAIT(6);
        BAR();
        LGKM_WAIT(8);
        __builtin_amdgcn_s_setprio(1);
#pragma unroll
        for (int ii = 0; ii < 4; ++ii)
#pragma unroll
            for (int jj = 0; jj < 2; ++jj)
#pragma unroll
                for (int ks = 0; ks < 2; ++ks)
                    acc[ii][2 + jj] = __builtin_amdgcn_mfma_f32_16x16x32_bf16(alo[ii][ks], bhi[jj][ks], acc[ii][2 + jj], 0, 0, 0);
        __builtin_amdgcn_s_setprio(0);

        // ---- P3: rd alo(t+1) from nxt; stage AL13(t+2) ----
        if (kt + 1 < KTILES) {
#pragma unroll
            for (int ii = 0; ii < 4; ++ii) { alo[ii][0] = RDF(aTn, ii, 0); alo[ii][1] = RDF(aTn, ii, 1); }
        }
        if (kt + 2 < KTILES) {
            gload_lds16(Ag2,                 An + dsub);
            gload_lds16(Ag2 + 128 * D_MODEL, An + 8192 + dsub);
        }
        BAR();
        if (kt + 1 < KTILES) { LGKM_WAIT(8); } else { LGKM_WAIT(0); }
        __builtin_amdgcn_s_setprio(1);
#pragma unroll
        for (int ii = 0; ii < 4; ++ii)
#pragma unroll
            for (int jj = 0; jj < 2; ++jj)
#pragma unroll
                for (int ks = 0; ks < 2; ++ks)
                    acc[4 + ii][2 + jj] = __builtin_amdgcn_mfma_f32_16x16x32_bf16(ahi[ii][ks], bhi[jj][ks], acc[4 + ii][2 + jj], 0, 0, 0);
        __builtin_amdgcn_s_setprio(0);

        // ---- P4: stage AL24(t+2); vmcnt(4) covers B(t+1)+AL24(t+1); Q4; rd blo(t+1) ----
        if (kt + 2 < KTILES) {
            gload_lds16(Ag2 +  64 * D_MODEL, An +  4096 + dsub);
            gload_lds16(Ag2 + 192 * D_MODEL, An + 12288 + dsub);
        }
        if (kt < KTILES - 2) { VM_WAIT(4); } else { VM_WAIT(0); }
        BAR();
        LGKM_WAIT(8);
        __builtin_amdgcn_s_setprio(1);
#pragma unroll
        for (int ii = 0; ii < 4; ++ii)
#pragma unroll
            for (int jj = 0; jj < 2; ++jj)
#pragma unroll
                for (int ks = 0; ks < 2; ++ks)
                    acc[4 + ii][jj] = __builtin_amdgcn_mfma_f32_16x16x32_bf16(ahi[ii][ks], blo[jj][ks], acc[4 + ii][jj], 0, 0, 0);
        __builtin_amdgcn_s_setprio(0);
        if (kt + 1 < KTILES) {
#pragma unroll
            for (int jj = 0; jj < 2; ++jj) { blo[jj][0] = RDF(bTn, jj, 0); blo[jj][1] = RDF(bTn, jj, 1); }
        }
    }
#undef RDF
}

// ---------------- projection GEMM: C = act(A . W^T). MODE 0: ternary, 1: sigmoid ----
template <int MODE>
__global__ __launch_bounds__(512, 2) void gemm256_proj(
    const bf16* __restrict__ A0, const bf16* __restrict__ A1,
    const bf16* __restrict__ W0, const bf16* __restrict__ W1,
    bf16* __restrict__ O0, bf16* __restrict__ O1)
{
    const bf16* A = blockIdx.y ? A1 : A0;
    const bf16* W = blockIdx.y ? W1 : W0;
    bf16* O       = blockIdx.y ? O1 : O0;

    __shared__ bf16 As[2][2][8192];
    __shared__ bf16 Bs[2][2][8192];
    int m0, n0;
    tile_coords256(blockIdx.x, m0, n0);

    f32x4 acc[8][4] = {};
    gemm256_core(A, W, &As[0][0][0], &Bs[0][0][0], m0, n0, acc);

    const int lane = threadIdx.x & 63, wave = threadIdx.x >> 6;
    const int wm = wave >> 2, wn = wave & 3;
    const int mf = lane & 15, quad = lane >> 4;
#pragma unroll
    for (int i = 0; i < 8; ++i)
#pragma unroll
        for (int j = 0; j < 4; ++j)
#pragma unroll
            for (int e = 0; e < 4; ++e) {
                const int row = m0 + wm * 128 + i * 16 + quad * 4 + e;
                const int col = n0 + wn * 64 + j * 16 + mf;
                const float v = acc[i][j][e];
                float o;
                if (MODE == 0) o = (v > 0.5f) ? 1.0f : ((v < -0.5f) ? -1.0f : 0.0f);
                else           o = 1.0f / (1.0f + __expf(-v));
                O[(size_t)row * D_MODEL + col] = f2bf(o);
            }
}

// ---------------- output GEMM with residual epilogue ----------------
__global__ __launch_bounds__(512, 2) void gemm256_out(
    const bf16* __restrict__ SA, const bf16* __restrict__ Wo,
    const bf16* __restrict__ R, const float* __restrict__ x, float* __restrict__ out)
{
    __shared__ bf16 As[2][2][8192];
    __shared__ bf16 Bs[2][2][8192];
    int m0, n0;
    tile_coords256(blockIdx.x, m0, n0);

    f32x4 acc[8][4] = {};
    gemm256_core(SA, Wo, &As[0][0][0], &Bs[0][0][0], m0, n0, acc);

    const int lane = threadIdx.x & 63, wave = threadIdx.x >> 6;
    const int wm = wave >> 2, wn = wave & 3;
    const int mf = lane & 15, quad = lane >> 4;
#pragma unroll
    for (int i = 0; i < 8; ++i)
#pragma unroll
        for (int j = 0; j < 4; ++j)
#pragma unroll
            for (int e = 0; e < 4; ++e) {
                const int row = m0 + wm * 128 + i * 16 + quad * 4 + e;
                const int col = n0 + wn * 64 + j * 16 + mf;
                const size_t o = (size_t)row * D_MODEL + col;
                out[o] = x[o] + bf2f(R[o]) * acc[i][j][e];
            }
}

// ---------------- recurrent scan: kv is ternary -> pack int8 in LDS, ----------------
// ---------------- pass 2 replays from LDS (saves 64 MB HBM re-read)  ----------------
__global__ __launch_bounds__(256) void scan_kernel(
    const bf16* __restrict__ K, const bf16* __restrict__ V,
    const float* __restrict__ dw, const float* __restrict__ S0,
    bf16* __restrict__ sall, float* __restrict__ sfinal)
{
    const int ch = threadIdx.x & 63;   // channel within group
    const int q  = threadIdx.x >> 6;   // T-chunk 0..3
    const int d  = blockIdx.x * 64 + ch;
    const int b  = blockIdx.y;
    const float dec = 1.0f / (1.0f + __expf(-dw[d]));
    float c256 = dec;
#pragma unroll
    for (int i = 0; i < 8; i++) c256 *= c256;   // dec^256

    const size_t base = ((size_t)b * SEQ + q * 256) * D_MODEL + d;

    __shared__ unsigned int kvp[4][64][64];     // [q][t/4][ch] 4 packed int8
    __shared__ float Lf[4][64];
    __shared__ float P[4][64];

    // pass 1: local scan (zero-init); pack kv (ternary, exact) into LDS
    float S = 0.f;
    size_t idx = base;
    unsigned int w = 0;
    for (int t = 0; t < 256; t++, idx += D_MODEL) {
        const float p = bf2f(K[idx]) * bf2f(V[idx]);   // in {-1, 0, 1}
        S = dec * S + p;
        w |= ((unsigned int)((int)p & 255)) << ((t & 3) * 8);
        if ((t & 3) == 3) { kvp[q][t >> 2][ch] = w; w = 0; }
    }

    Lf[q][ch] = S;
    __syncthreads();
    if (q == 0) {
        float p = S0[b * D_MODEL + d];      // true S_{-1}
        P[0][ch] = p;
        p = Lf[0][ch] + c256 * p; P[1][ch] = p;
        p = Lf[1][ch] + c256 * p; P[2][ch] = p;
        p = Lf[2][ch] + c256 * p; P[3][ch] = p;
        p = Lf[3][ch] + c256 * p;
        sfinal[b * D_MODEL + d] = p;
    }
    __syncthreads();

    // pass 2: replay from LDS with true incoming carry, store
    float Sv = P[q][ch];
    idx = base;
    for (int t4 = 0; t4 < 64; ++t4) {
        const unsigned int pw = kvp[q][t4][ch];
#pragma unroll
        for (int j = 0; j < 4; ++j, idx += D_MODEL) {
            const float p = (float)((int)(pw << (24 - 8 * j)) >> 24);
            Sv = dec * Sv + p;
            sall[idx] = f2bf(Sv);
        }
    }
}

extern "C" void kernel_launch(void* const* d_in, const int* in_sizes, int n_in,
                              void* d_out, int out_size, void* d_ws, size_t ws_size,
                              hipStream_t stream) {
    const float* x     = (const float*)d_in[0];
    const float* S0    = (const float*)d_in[1];
    const float* gamma = (const float*)d_in[2];
    const float* beta  = (const float*)d_in[3];
    const float* tmk   = (const float*)d_in[4];
    const float* tmv   = (const float*)d_in[5];
    const float* tmr   = (const float*)d_in[6];
    const float* dw    = (const float*)d_in[7];
    const float* Wk    = (const float*)d_in[8];
    const float* Wv    = (const float*)d_in[9];
    const float* Wr    = (const float*)d_in[10];
    const float* Wo    = (const float*)d_in[11];
    float* out = (float*)d_out;

    const int WN = D_MODEL * D_MODEL;             // 1048576
    const size_t MATN = (size_t)NROWS * D_MODEL;  // 16777216

    // 8 MB weights + 5 x 32 MB matrix slots = 168 MB
    bf16* wsb  = (bf16*)d_ws;
    bf16* Wk_b = wsb;
    bf16* Wv_b = Wk_b + WN;
    bf16* Wr_b = Wv_b + WN;
    bf16* Wo_b = Wr_b + WN;
    bf16* XK = Wo_b + WN;     // slot0: XK,  later RB (XK dead after gemm_kv)
    bf16* XV = XK + MATN;     // slot1: XV,  later SA (XV dead after gemm_kv)
    bf16* XR = XV + MATN;     // slot2: XR
    bf16* Kt = XR + MATN;     // slot3
    bf16* Vt = Kt + MATN;     // slot4
    bf16* RB = XK;
    bf16* SA = XV;

    conv_w4_kernel<<<dim3(256, 4), 256, 0, stream>>>(Wk, Wv, Wr, Wo, wsb);

    lnmix_kernel<<<NROWS / 4, 256, 0, stream>>>(x, gamma, beta, tmk, tmv, tmr, XK, XV, XR);

    // K and V projections in one dispatch (independent blocks)
    gemm256_proj<0><<<dim3(256, 2), 512, 0, stream>>>(XK, XV, Wk_b, Wv_b, Kt, Vt);

    // R projection (XK now dead -> RB reuses slot0)
    gemm256_proj<1><<<dim3(256, 1), 512, 0, stream>>>(XR, XR, Wr_b, Wr_b, RB, RB);

    // scan (XV now dead -> SA reuses slot1)
    scan_kernel<<<dim3(D_MODEL / 64, BATCH), 256, 0, stream>>>(Kt, Vt, dw, S0, SA, out + MATN);

    gemm256_out<<<dim3(256, 1), 512, 0, stream>>>(SA, Wo_b, RB, x, out);
}

// Round 4
// 345.707 us; speedup vs baseline: 1.0502x; 1.0502x over previous
//
#include <hip/hip_runtime.h>
#include <hip/hip_bf16.h>
#include <math.h>

#define D_MODEL 1024
#define SEQ 1024
#define BATCH 16
#define NROWS (BATCH * SEQ)   // 16384
#define KTILES 16             // D_MODEL / 64

typedef __bf16 bf16x8 __attribute__((ext_vector_type(8)));
typedef __bf16 bf16x4 __attribute__((ext_vector_type(4)));
typedef float f32x4 __attribute__((ext_vector_type(4)));
typedef __hip_bfloat16 bf16;

__device__ __forceinline__ float bf2f(bf16 v) { return __bfloat162float(v); }
__device__ __forceinline__ bf16 f2bf(float v) { return __float2bfloat16(v); }

__device__ __forceinline__ void gload_lds16(const bf16* g, bf16* l) {
    __builtin_amdgcn_global_load_lds(
        (const __attribute__((address_space(1))) void*)g,
        (__attribute__((address_space(3))) void*)l, 16, 0, 0);
}

#define VM_WAIT(n)   asm volatile("s_waitcnt vmcnt(" #n ")" ::: "memory")
#define LGKM_WAIT(n) asm volatile("s_waitcnt lgkmcnt(" #n ")" ::: "memory")
#define BAR()        __builtin_amdgcn_s_barrier()

// 256 blocks -> 8 XCDs x 32. Each XCD: 8 M-bands x 4 N-tiles concurrent.
__device__ __forceinline__ void tile_coords256(int lin, int& m0, int& n0) {
    const int xcd = lin & 7;
    const int loc = lin >> 3;            // 0..31
    m0 = (xcd * 8 + (loc >> 2)) * 256;
    n0 = (loc & 3) * 256;
}

// ---------------- all 4 weights fp32 -> bf16, one dispatch (vectorized) ----------------
__global__ void conv_w4_kernel(const float* __restrict__ s0, const float* __restrict__ s1,
                               const float* __restrict__ s2, const float* __restrict__ s3,
                               bf16* __restrict__ dst) {
    const float* srcs[4] = {s0, s1, s2, s3};
    const float* src = srcs[blockIdx.y];
    bf16* d = dst + (size_t)blockIdx.y * (D_MODEL * D_MODEL);
    int i = blockIdx.x * blockDim.x + threadIdx.x;
    const int stride = gridDim.x * blockDim.x;
    for (; i < (D_MODEL * D_MODEL) / 4; i += stride) {
        float4 f = reinterpret_cast<const float4*>(src)[i];
        bf16x4 o;
        o[0] = (__bf16)f.x; o[1] = (__bf16)f.y; o[2] = (__bf16)f.z; o[3] = (__bf16)f.w;
        reinterpret_cast<bf16x4*>(d)[i] = o;
    }
}

// ---------------- fused LayerNorm + time-mix: one wave per row ----------------
// XCD-banded block swizzle: consecutive rows stay on one XCD so the prev-row
// re-read (row t-1 fetched by both block b and b-1) hits that XCD's L2.
__global__ __launch_bounds__(256) void lnmix_kernel(
    const float* __restrict__ x, const float* __restrict__ gamma, const float* __restrict__ beta,
    const float* __restrict__ tmk, const float* __restrict__ tmv, const float* __restrict__ tmr,
    bf16* __restrict__ xk, bf16* __restrict__ xv, bf16* __restrict__ xr)
{
    const int wave = threadIdx.x >> 6, lane = threadIdx.x & 63;
    const int lb = (blockIdx.x & 7) * (gridDim.x >> 3) + (blockIdx.x >> 3);
    const int row = lb * 4 + wave;
    const int t = row & (SEQ - 1);
    const size_t base = (size_t)row * D_MODEL;

    float4 vc[4], vp[4];
    float sc = 0.f, sc2 = 0.f, sp = 0.f, sp2 = 0.f;
#pragma unroll
    for (int c = 0; c < 4; c++) {
        const int d = lane * 4 + c * 256;
        vc[c] = *reinterpret_cast<const float4*>(x + base + d);
        if (t == 0) { vp[c] = make_float4(0.f, 0.f, 0.f, 0.f); }
        else        { vp[c] = *reinterpret_cast<const float4*>(x + base - D_MODEL + d); }
        sc  += vc[c].x + vc[c].y + vc[c].z + vc[c].w;
        sc2 += vc[c].x * vc[c].x + vc[c].y * vc[c].y + vc[c].z * vc[c].z + vc[c].w * vc[c].w;
        sp  += vp[c].x + vp[c].y + vp[c].z + vp[c].w;
        sp2 += vp[c].x * vp[c].x + vp[c].y * vp[c].y + vp[c].z * vp[c].z + vp[c].w * vp[c].w;
    }
#pragma unroll
    for (int off = 1; off < 64; off <<= 1) {
        sc  += __shfl_xor(sc, off);
        sc2 += __shfl_xor(sc2, off);
        sp  += __shfl_xor(sp, off);
        sp2 += __shfl_xor(sp2, off);
    }
    const float muc = sc * (1.0f / D_MODEL);
    const float rc  = rsqrtf(sc2 * (1.0f / D_MODEL) - muc * muc + 1e-5f);
    const float mup = sp * (1.0f / D_MODEL);
    const float rp  = rsqrtf(sp2 * (1.0f / D_MODEL) - mup * mup + 1e-5f);

#pragma unroll
    for (int c = 0; c < 4; c++) {
        const int d = lane * 4 + c * 256;
        float4 g  = *reinterpret_cast<const float4*>(gamma + d);
        float4 b  = *reinterpret_cast<const float4*>(beta + d);
        float4 mk = *reinterpret_cast<const float4*>(tmk + d);
        float4 mv = *reinterpret_cast<const float4*>(tmv + d);
        float4 mr = *reinterpret_cast<const float4*>(tmr + d);
        float cn[4], pn[4];
        cn[0] = (vc[c].x - muc) * rc * g.x + b.x;
        cn[1] = (vc[c].y - muc) * rc * g.y + b.y;
        cn[2] = (vc[c].z - muc) * rc * g.z + b.z;
        cn[3] = (vc[c].w - muc) * rc * g.w + b.w;
        if (t == 0) { pn[0] = pn[1] = pn[2] = pn[3] = 0.f; }
        else {
            pn[0] = (vp[c].x - mup) * rp * g.x + b.x;
            pn[1] = (vp[c].y - mup) * rp * g.y + b.y;
            pn[2] = (vp[c].z - mup) * rp * g.z + b.z;
            pn[3] = (vp[c].w - mup) * rp * g.w + b.w;
        }
        const float mkv[4] = {mk.x, mk.y, mk.z, mk.w};
        const float mvv[4] = {mv.x, mv.y, mv.z, mv.w};
        const float mrv[4] = {mr.x, mr.y, mr.z, mr.w};
        bf16x4 ok, ov, orr;
#pragma unroll
        for (int e = 0; e < 4; e++) {
            ok[e]  = (__bf16)(mkv[e] * cn[e] + (1.0f - mkv[e]) * pn[e]);
            ov[e]  = (__bf16)(mvv[e] * cn[e] + (1.0f - mvv[e]) * pn[e]);
            orr[e] = (__bf16)(mrv[e] * cn[e] + (1.0f - mrv[e]) * pn[e]);
        }
        *reinterpret_cast<bf16x4*>(xk + base + d) = ok;
        *reinterpret_cast<bf16x4*>(xv + base + d) = ov;
        *reinterpret_cast<bf16x4*>(xr + base + d) = orr;
    }
}

// ============================================================================
// 256x256 GEMM core (unchanged from R3 best: cross-phase fragment prefetch).
// ============================================================================
__device__ __forceinline__ void gemm256_core(
    const bf16* __restrict__ A, const bf16* __restrict__ W,
    bf16* __restrict__ AsB, bf16* __restrict__ BsB,
    int m0, int n0, f32x4 (&acc)[8][4])
{
    const int tid  = threadIdx.x;
    const int wave = tid >> 6, lane = tid & 63;
    const int wm = wave >> 2, wn = wave & 3;
    const int mf = lane & 15, quad = lane >> 4;
    const int srow = tid >> 3;                       // 0..63
    const int scol = ((tid & 7) ^ (srow & 7)) * 8;   // pre-swizzled source chunk
    const int dsub = wave * 512;                     // wave-uniform LDS dest base

    const bf16* Ag = A + (size_t)(m0 + srow) * D_MODEL + scol;
    const bf16* Bg = W + (size_t)(n0 + srow) * D_MODEL + scol;

    bf16x8 alo[4][2], ahi[4][2], blo[2][2], bhi[2][2];

#define RDF(base, R, C) (*reinterpret_cast<const bf16x8*>( \
        (base) + ((R) * 16 + mf) * 64 + ((((C) * 4 + quad) ^ (mf & 7)) * 8)))

    // ---- prologue: t0 {AL13,AL24,B12,B34} + t1 {AL13,AL24} (12 gloads) ----
    gload_lds16(Ag,                   AsB + dsub);               // t0.AL1
    gload_lds16(Ag + 128 * D_MODEL,   AsB +  8192 + dsub);       // t0.AL3
    gload_lds16(Ag +  64 * D_MODEL,   AsB +  4096 + dsub);       // t0.AL2
    gload_lds16(Ag + 192 * D_MODEL,   AsB + 12288 + dsub);       // t0.AL4
    gload_lds16(Bg,                   BsB + dsub);               // t0.B1
    gload_lds16(Bg +  64 * D_MODEL,   BsB +  4096 + dsub);       // t0.B2
    gload_lds16(Bg + 128 * D_MODEL,   BsB +  8192 + dsub);       // t0.B3
    gload_lds16(Bg + 192 * D_MODEL,   BsB + 12288 + dsub);       // t0.B4
    gload_lds16(Ag +                64, AsB + 16384 + dsub);           // t1.AL1
    gload_lds16(Ag + 128 * D_MODEL + 64, AsB + 16384 +  8192 + dsub);  // t1.AL3
    gload_lds16(Ag +  64 * D_MODEL + 64, AsB + 16384 +  4096 + dsub);  // t1.AL2
    gload_lds16(Ag + 192 * D_MODEL + 64, AsB + 16384 + 12288 + dsub);  // t1.AL4
    VM_WAIT(4);                      // t0's 8 landed; t1's A halves still fly
    BAR();

    // pre-read tile0's alo + blo (consumed by kt=0 P1/Q1)
    {
        const bf16* aT0 = AsB + wm * 8192;
        const bf16* bT0 = BsB + wn * 4096;
#pragma unroll
        for (int ii = 0; ii < 4; ++ii) { alo[ii][0] = RDF(aT0, ii, 0); alo[ii][1] = RDF(aT0, ii, 1); }
#pragma unroll
        for (int jj = 0; jj < 2; ++jj) { blo[jj][0] = RDF(bT0, jj, 0); blo[jj][1] = RDF(bT0, jj, 1); }
    }

#pragma unroll 2
    for (int kt = 0; kt < KTILES; ++kt) {
        const int cur = kt & 1;
        const bf16* aT  = AsB + cur * 16384 + wm * 8192;
        const bf16* bT  = BsB + cur * 16384 + wn * 4096;
        const bf16* aTn = AsB + (cur ^ 1) * 16384 + wm * 8192;
        const bf16* bTn = BsB + (cur ^ 1) * 16384 + wn * 4096;
        bf16* An = AsB + cur * 16384;            // A stage target (t+2 -> cur)
        bf16* Bn = BsB + (cur ^ 1) * 16384;      // B stage target (t+1 -> nxt)
        const bf16* Ag2 = Ag + (kt + 2) * 64;
        const bf16* Bg1 = Bg + (kt + 1) * 64;

        // ---- P1: rd bhi(t); stage B12(t+1) ----
#pragma unroll
        for (int jj = 0; jj < 2; ++jj) { bhi[jj][0] = RDF(bT, 2 + jj, 0); bhi[jj][1] = RDF(bT, 2 + jj, 1); }
        if (kt + 1 < KTILES) {
            gload_lds16(Bg1,                Bn + dsub);
            gload_lds16(Bg1 + 64 * D_MODEL, Bn + 4096 + dsub);
        }
        BAR();
        LGKM_WAIT(4);
        __builtin_amdgcn_s_setprio(1);
#pragma unroll
        for (int ii = 0; ii < 4; ++ii)
#pragma unroll
            for (int jj = 0; jj < 2; ++jj)
#pragma unroll
                for (int ks = 0; ks < 2; ++ks)
                    acc[ii][jj] = __builtin_amdgcn_mfma_f32_16x16x32_bf16(alo[ii][ks], blo[jj][ks], acc[ii][jj], 0, 0, 0);
        __builtin_amdgcn_s_setprio(0);

        // ---- P2: rd ahi(t); stage B34(t+1); vmcnt(6) covers AL13(t+1) ----
#pragma unroll
        for (int ii = 0; ii < 4; ++ii) { ahi[ii][0] = RDF(aT, 4 + ii, 0); ahi[ii][1] = RDF(aT, 4 + ii, 1); }
        if (kt + 1 < KTILES) {
            gload_lds16(Bg1 + 128 * D_MODEL, Bn +  8192 + dsub);
            gload_lds16(Bg1 + 192 * D_MODEL, Bn + 12288 + dsub);
        }
        VM_WAIT(6);
        BAR();
        LGKM_WAIT(8);
        __builtin_amdgcn_s_setprio(1);
#pragma unroll
        for (int ii = 0; ii < 4; ++ii)
#pragma unroll
            for (int jj = 0; jj < 2; ++jj)
#pragma unroll
                for (int ks = 0; ks < 2; ++ks)
                    acc[ii][2 + jj] = __builtin_amdgcn_mfma_f32_16x16x32_bf16(alo[ii][ks], bhi[jj][ks], acc[ii][2 + jj], 0, 0, 0);
        __builtin_amdgcn_s_setprio(0);

        // ---- P3: rd alo(t+1) from nxt; stage AL13(t+2) ----
        if (kt + 1 < KTILES) {
#pragma unroll
            for (int ii = 0; ii < 4; ++ii) { alo[ii][0] = RDF(aTn, ii, 0); alo[ii][1] = RDF(aTn, ii, 1); }
        }
        if (kt + 2 < KTILES) {
            gload_lds16(Ag2,                 An + dsub);
            gload_lds16(Ag2 + 128 * D_MODEL, An + 8192 + dsub);
        }
        BAR();
        if (kt + 1 < KTILES) { LGKM_WAIT(8); } else { LGKM_WAIT(0); }
        __builtin_amdgcn_s_setprio(1);
#pragma unroll
        for (int ii = 0; ii < 4; ++ii)
#pragma unroll
            for (int jj = 0; jj < 2; ++jj)
#pragma unroll
                for (int ks = 0; ks < 2; ++ks)
                    acc[4 + ii][2 + jj] = __builtin_amdgcn_mfma_f32_16x16x32_bf16(ahi[ii][ks], bhi[jj][ks], acc[4 + ii][2 + jj], 0, 0, 0);
        __builtin_amdgcn_s_setprio(0);

        // ---- P4: stage AL24(t+2); vmcnt(4); Q4; rd blo(t+1) ----
        if (kt + 2 < KTILES) {
            gload_lds16(Ag2 +  64 * D_MODEL, An +  4096 + dsub);
            gload_lds16(Ag2 + 192 * D_MODEL, An + 12288 + dsub);
        }
        if (kt < KTILES - 2) { VM_WAIT(4); } else { VM_WAIT(0); }
        BAR();
        LGKM_WAIT(8);
        __builtin_amdgcn_s_setprio(1);
#pragma unroll
        for (int ii = 0; ii < 4; ++ii)
#pragma unroll
            for (int jj = 0; jj < 2; ++jj)
#pragma unroll
                for (int ks = 0; ks < 2; ++ks)
                    acc[4 + ii][jj] = __builtin_amdgcn_mfma_f32_16x16x32_bf16(ahi[ii][ks], blo[jj][ks], acc[4 + ii][jj], 0, 0, 0);
        __builtin_amdgcn_s_setprio(0);
        if (kt + 1 < KTILES) {
#pragma unroll
            for (int jj = 0; jj < 2; ++jj) { blo[jj][0] = RDF(bTn, jj, 0); blo[jj][1] = RDF(bTn, jj, 1); }
        }
    }
#undef RDF
}

// ---------------- K,V projections (ternary), one dispatch ----------------
__global__ __launch_bounds__(512, 2) void gemm256_proj(
    const bf16* __restrict__ A0, const bf16* __restrict__ A1,
    const bf16* __restrict__ W0, const bf16* __restrict__ W1,
    bf16* __restrict__ O0, bf16* __restrict__ O1)
{
    const bf16* A = blockIdx.y ? A1 : A0;
    const bf16* W = blockIdx.y ? W1 : W0;
    bf16* O       = blockIdx.y ? O1 : O0;

    __shared__ bf16 As[2][2][8192];
    __shared__ bf16 Bs[2][2][8192];
    int m0, n0;
    tile_coords256(blockIdx.x, m0, n0);

    f32x4 acc[8][4] = {};
    gemm256_core(A, W, &As[0][0][0], &Bs[0][0][0], m0, n0, acc);

    const int lane = threadIdx.x & 63, wave = threadIdx.x >> 6;
    const int wm = wave >> 2, wn = wave & 3;
    const int mf = lane & 15, quad = lane >> 4;
#pragma unroll
    for (int i = 0; i < 8; ++i)
#pragma unroll
        for (int j = 0; j < 4; ++j)
#pragma unroll
            for (int e = 0; e < 4; ++e) {
                const int row = m0 + wm * 128 + i * 16 + quad * 4 + e;
                const int col = n0 + wn * 64 + j * 16 + mf;
                const float v = acc[i][j][e];
                const float o = (v > 0.5f) ? 1.0f : ((v < -0.5f) ? -1.0f : 0.0f);
                O[(size_t)row * D_MODEL + col] = f2bf(o);
            }
}

// ---------------- merged: R projection (sigmoid) + recurrent scan ----------------
// blocks 0..255: R = sigmoid(XR . Wr^T) -> RB. blocks 256..511: scan.
// Scan: 8 T-chunks x 128 steps/thread (512 thr = 64 ch x 8 chunks), unroll-4
// batched loads in pass 1; ternary kv packed int8 in LDS; pass 2 replays from
// LDS (no HBM re-read); cross-chunk carry fix via dec^128.
__global__ __launch_bounds__(512, 2) void rproj_scan_kernel(
    const bf16* __restrict__ XR, const bf16* __restrict__ WrB, bf16* __restrict__ RB,
    const bf16* __restrict__ K, const bf16* __restrict__ V,
    const float* __restrict__ dw, const float* __restrict__ S0,
    bf16* __restrict__ sall, float* __restrict__ sfinal)
{
    __shared__ __align__(16) char smem[131072];

    if (blockIdx.x < 256) {
        bf16* As = reinterpret_cast<bf16*>(smem);            // 64 KB
        bf16* Bs = reinterpret_cast<bf16*>(smem + 65536);    // 64 KB
        int m0, n0;
        tile_coords256(blockIdx.x, m0, n0);

        f32x4 acc[8][4] = {};
        gemm256_core(XR, WrB, As, Bs, m0, n0, acc);

        const int lane = threadIdx.x & 63, wave = threadIdx.x >> 6;
        const int wm = wave >> 2, wn = wave & 3;
        const int mf = lane & 15, quad = lane >> 4;
#pragma unroll
        for (int i = 0; i < 8; ++i)
#pragma unroll
            for (int j = 0; j < 4; ++j)
#pragma unroll
                for (int e = 0; e < 4; ++e) {
                    const int row = m0 + wm * 128 + i * 16 + quad * 4 + e;
                    const int col = n0 + wn * 64 + j * 16 + mf;
                    const float v = acc[i][j][e];
                    RB[(size_t)row * D_MODEL + col] = f2bf(1.0f / (1.0f + __expf(-v)));
                }
        return;
    }

    // ---------------- scan half ----------------
    unsigned int* kvp = reinterpret_cast<unsigned int*>(smem);        // [8][32][64] = 64 KB
    float* Lf = reinterpret_cast<float*>(smem + 65536);               // [8][64]
    float* P  = reinterpret_cast<float*>(smem + 65536 + 2048);        // [8][64]

    const int bid = blockIdx.x - 256;      // 0..255
    const int db  = bid & 15, b = bid >> 4;
    const int ch  = threadIdx.x & 63;      // channel within group
    const int q   = threadIdx.x >> 6;      // T-chunk 0..7
    const int d   = db * 64 + ch;

    const float dec = 1.0f / (1.0f + __expf(-dw[d]));
    float c128 = dec;
#pragma unroll
    for (int i = 0; i < 7; i++) c128 *= c128;   // dec^128

    const size_t base = ((size_t)b * SEQ + q * 128) * D_MODEL + d;

    // pass 1: local scan (zero-init), batched loads, pack kv into LDS
    float S = 0.f;
    size_t idx = base;
    for (int t = 0; t < 128; t += 4, idx += 4 * D_MODEL) {
        const float k0 = bf2f(K[idx]);
        const float v0 = bf2f(V[idx]);
        const float k1 = bf2f(K[idx + 1 * D_MODEL]);
        const float v1 = bf2f(V[idx + 1 * D_MODEL]);
        const float k2 = bf2f(K[idx + 2 * D_MODEL]);
        const float v2 = bf2f(V[idx + 2 * D_MODEL]);
        const float k3 = bf2f(K[idx + 3 * D_MODEL]);
        const float v3 = bf2f(V[idx + 3 * D_MODEL]);
        const float p0 = k0 * v0, p1 = k1 * v1, p2 = k2 * v2, p3 = k3 * v3;
        S = dec * S + p0;
        S = dec * S + p1;
        S = dec * S + p2;
        S = dec * S + p3;
        const unsigned int w =
            ((unsigned int)((int)p0 & 255)) |
            ((unsigned int)((int)p1 & 255) << 8) |
            ((unsigned int)((int)p2 & 255) << 16) |
            ((unsigned int)((int)p3 & 255) << 24);
        kvp[(q * 32 + (t >> 2)) * 64 + ch] = w;
    }

    Lf[q * 64 + ch] = S;
    __syncthreads();
    if (q == 0) {
        float p = S0[b * D_MODEL + d];      // true S_{-1}
        P[ch] = p;
#pragma unroll
        for (int j = 1; j < 8; ++j) {
            p = Lf[(j - 1) * 64 + ch] + c128 * p;
            P[j * 64 + ch] = p;
        }
        p = Lf[7 * 64 + ch] + c128 * p;
        sfinal[b * D_MODEL + d] = p;
    }
    __syncthreads();

    // pass 2: replay from LDS with true incoming carry, store
    float Sv = P[q * 64 + ch];
    idx = base;
    for (int t4 = 0; t4 < 32; ++t4) {
        const unsigned int pw = kvp[(q * 32 + t4) * 64 + ch];
#pragma unroll
        for (int j = 0; j < 4; ++j, idx += D_MODEL) {
            const float p = (float)((int)(pw << (24 - 8 * j)) >> 24);
            Sv = dec * Sv + p;
            sall[idx] = f2bf(Sv);
        }
    }
}

// ---------------- output GEMM with residual epilogue ----------------
__global__ __launch_bounds__(512, 2) void gemm256_out(
    const bf16* __restrict__ SA, const bf16* __restrict__ Wo,
    const bf16* __restrict__ R, const float* __restrict__ x, float* __restrict__ out)
{
    __shared__ bf16 As[2][2][8192];
    __shared__ bf16 Bs[2][2][8192];
    int m0, n0;
    tile_coords256(blockIdx.x, m0, n0);

    f32x4 acc[8][4] = {};
    gemm256_core(SA, Wo, &As[0][0][0], &Bs[0][0][0], m0, n0, acc);

    const int lane = threadIdx.x & 63, wave = threadIdx.x >> 6;
    const int wm = wave >> 2, wn = wave & 3;
    const int mf = lane & 15, quad = lane >> 4;
#pragma unroll
    for (int i = 0; i < 8; ++i)
#pragma unroll
        for (int j = 0; j < 4; ++j)
#pragma unroll
            for (int e = 0; e < 4; ++e) {
                const int row = m0 + wm * 128 + i * 16 + quad * 4 + e;
                const int col = n0 + wn * 64 + j * 16 + mf;
                const size_t o = (size_t)row * D_MODEL + col;
                out[o] = x[o] + bf2f(R[o]) * acc[i][j][e];
            }
}

extern "C" void kernel_launch(void* const* d_in, const int* in_sizes, int n_in,
                              void* d_out, int out_size, void* d_ws, size_t ws_size,
                              hipStream_t stream) {
    const float* x     = (const float*)d_in[0];
    const float* S0    = (const float*)d_in[1];
    const float* gamma = (const float*)d_in[2];
    const float* beta  = (const float*)d_in[3];
    const float* tmk   = (const float*)d_in[4];
    const float* tmv   = (const float*)d_in[5];
    const float* tmr   = (const float*)d_in[6];
    const float* dw    = (const float*)d_in[7];
    const float* Wk    = (const float*)d_in[8];
    const float* Wv    = (const float*)d_in[9];
    const float* Wr    = (const float*)d_in[10];
    const float* Wo    = (const float*)d_in[11];
    float* out = (float*)d_out;

    const int WN = D_MODEL * D_MODEL;             // 1048576
    const size_t MATN = (size_t)NROWS * D_MODEL;  // 16777216

    // 8 MB weights + 5 x 32 MB matrix slots = 168 MB
    bf16* wsb  = (bf16*)d_ws;
    bf16* Wk_b = wsb;
    bf16* Wv_b = Wk_b + WN;
    bf16* Wr_b = Wv_b + WN;
    bf16* Wo_b = Wr_b + WN;
    bf16* XK = Wo_b + WN;     // slot0: XK,  later RB (XK dead after gemm_kv)
    bf16* XV = XK + MATN;     // slot1: XV,  later SA (XV dead after gemm_kv)
    bf16* XR = XV + MATN;     // slot2: XR
    bf16* Kt = XR + MATN;     // slot3
    bf16* Vt = Kt + MATN;     // slot4
    bf16* RB = XK;
    bf16* SA = XV;

    conv_w4_kernel<<<dim3(128, 4), 256, 0, stream>>>(Wk, Wv, Wr, Wo, wsb);

    lnmix_kernel<<<NROWS / 4, 256, 0, stream>>>(x, gamma, beta, tmk, tmv, tmr, XK, XV, XR);

    // K and V projections in one dispatch (independent blocks)
    gemm256_proj<<<dim3(256, 2), 512, 0, stream>>>(XK, XV, Wk_b, Wv_b, Kt, Vt);

    // merged: R projection (XK dead -> RB slot0) + scan (XV dead -> SA slot1)
    rproj_scan_kernel<<<512, 512, 0, stream>>>(XR, Wr_b, RB, Kt, Vt, dw, S0, SA, out + MATN);

    gemm256_out<<<256, 512, 0, stream>>>(SA, Wo_b, RB, x, out);
}